// Round 1
// 73.020 us; speedup vs baseline: 1.0089x; 1.0089x over previous
//
#include <hip/hip_runtime.h>

// GNNHierarchyModel: complete-graph GCN (N=1024) collapses to rank-1.
//   s = (1/1024) * sum_i emb[y[i]]          [64]
//   h = relu(s @ W1 + b1)                   [128]
//   o = h @ W2 + b2                         [64]
//   out[i,:] = o  for all 1024 rows         [1024,64] fp32
//
// Complete graph + self-loops => deg == 1024 uniformly => norm == 1/1024 and
// every output row equals the same mean-pooled MLP result. edge_index unused.
//
// R3 (this round): the timed graph contains a 256 MiB workspace poison fill
// (~42 us at HBM ceiling, untouchable) that also FLUSHES L2 every iteration,
// so every load here is an HBM cold miss (~900 cyc). Previous kernel's
// phase 1 was a 32-deep serial y->emb miss chain per thread (~25 us).
// This version:
//   * 512 thr/block, 16 contiguous rows per 8-lane group: 4 independent
//     int4 y-loads, then 32 independent float4 emb-loads -> ONE dependent
//     miss layer, all misses in flight at once.
//   * W1/W2/b1/b2 prefetched to registers at kernel start (issued alongside
//     the gather misses), staged to LDS; phases 2/3 read warm LDS.
//   * LDS partial-sum array padded to stride 65 (old layout: 8-way bank
//     conflict on the partial stores).

#define NTHREADS 512
#define NBLOCKS  16

__global__ __launch_bounds__(NTHREADS) void gnn_fused(
    const int*   __restrict__ y,
    const float* __restrict__ emb,
    const float* __restrict__ W1,
    const float* __restrict__ b1,
    const float* __restrict__ W2,
    const float* __restrict__ b2,
    float4*      __restrict__ out)   // 1024*64 fp32 = 16384 float4
{
    __shared__ float red[64][65];               // padded: conflict-free partials (16.25 KB)
    __shared__ float red2[8][64];               // 2 KB
    __shared__ __align__(16) float w1s[64*128]; // 32 KB
    __shared__ __align__(16) float w2s[128*64]; // 32 KB
    __shared__ float b2s[64];
    __shared__ float sv[64];
    __shared__ float hv[128];
    __shared__ __align__(16) float ov[64];

    const int tid = threadIdx.x;
    const int g   = tid >> 3;   // row group 0..63 (16 contiguous rows each)
    const int o8  = tid & 7;    // 8-column chunk 0..7

    // ---- issue y index loads first (independent cold misses)
    const int4* yv = (const int4*)(y + (g << 4));
    const int4 y0 = yv[0];
    const int4 y1 = yv[1];
    const int4 y2 = yv[2];
    const int4 y3 = yv[3];

    // ---- issue W/b prefetch loads (independent; latency hides under gather)
    const float4* W1v = (const float4*)W1;   // 2048 float4
    const float4* W2v = (const float4*)W2;   // 2048 float4
    const float4 wa0 = W1v[tid];
    const float4 wa1 = W1v[tid +  512];
    const float4 wa2 = W1v[tid + 1024];
    const float4 wa3 = W1v[tid + 1536];
    const float4 wb0 = W2v[tid];
    const float4 wb1 = W2v[tid +  512];
    const float4 wb2 = W2v[tid + 1024];
    const float4 wb3 = W2v[tid + 1536];
    float bb = 0.f;
    if (tid < 128)      bb = b1[tid];
    else if (tid < 192) bb = b2[tid - 128];

    // ---- gather: 16 rows x 8 cols per thread; one dependent layer (y -> emb)
    float acc[8];
    #pragma unroll
    for (int k = 0; k < 8; ++k) acc[k] = 0.f;

    const int idx[16] = { y0.x, y0.y, y0.z, y0.w,  y1.x, y1.y, y1.z, y1.w,
                          y2.x, y2.y, y2.z, y2.w,  y3.x, y3.y, y3.z, y3.w };
    #pragma unroll
    for (int j = 0; j < 16; ++j) {
        const float* p  = emb + (idx[j] << 6) + (o8 << 3);
        const float4 v0 = *(const float4*)p;
        const float4 v1 = *(const float4*)(p + 4);
        acc[0] += v0.x; acc[1] += v0.y; acc[2] += v0.z; acc[3] += v0.w;
        acc[4] += v1.x; acc[5] += v1.y; acc[6] += v1.z; acc[7] += v1.w;
    }

    // ---- stage W/b to LDS (data already landed while gather was in flight)
    float4* w1sv = (float4*)w1s;
    float4* w2sv = (float4*)w2s;
    w1sv[tid]        = wa0;
    w1sv[tid +  512] = wa1;
    w1sv[tid + 1024] = wa2;
    w1sv[tid + 1536] = wa3;
    w2sv[tid]        = wb0;
    w2sv[tid +  512] = wb1;
    w2sv[tid + 1024] = wb2;
    w2sv[tid + 1536] = wb3;
    if (tid >= 128 && tid < 192) b2s[tid - 128] = bb;

    // ---- partial sums (stride-65: bank = (g + o8*8 + k) & 31, conflict-free)
    #pragma unroll
    for (int k = 0; k < 8; ++k) red[g][(o8 << 3) + k] = acc[k];
    __syncthreads();

    // ---- reduce 64 groups -> 8 -> 1 per column
    {
        const int col = tid & 63, seg = tid >> 6;   // all 512 threads
        float t = 0.f;
        #pragma unroll
        for (int j = 0; j < 8; ++j) t += red[(seg << 3) + j][col];
        red2[seg][col] = t;
    }
    __syncthreads();
    if (tid < 64) {
        float t = 0.f;
        #pragma unroll
        for (int j = 0; j < 8; ++j) t += red2[j][tid];
        sv[tid] = t * (1.0f / 1024.0f);
    }
    __syncthreads();

    // ---- h = relu(s @ W1 + b1); one thread per hidden unit, W1 from LDS
    if (tid < 128) {
        float a = bb;                                // own b1[tid]
        #pragma unroll
        for (int k = 0; k < 64; ++k) a = fmaf(sv[k], w1s[k * 128 + tid], a);
        hv[tid] = fmaxf(a, 0.f);
    }
    __syncthreads();

    // ---- o = h @ W2 + b2; one thread per output column, W2 from LDS
    if (tid < 64) {
        float a = b2s[tid];
        #pragma unroll
        for (int k = 0; k < 128; ++k) a = fmaf(hv[k], w2s[k * 64 + tid], a);
        ov[tid] = a;
    }
    __syncthreads();

    // ---- broadcast o to this block's 64-row slice (coalesced 16B stores)
    const float4* o4  = (const float4*)ov;
    const int     base = (int)blockIdx.x * (16384 / NBLOCKS);
    out[base + tid]       = o4[tid & 15];
    out[base + tid + 512] = o4[tid & 15];
}

extern "C" void kernel_launch(void* const* d_in, const int* in_sizes, int n_in,
                              void* d_out, int out_size, void* d_ws, size_t ws_size,
                              hipStream_t stream) {
    const int* y      = (const int*)d_in[0];
    // d_in[1] = edge_index: unused (complete graph => norm == 1/1024 uniform)
    const float* emb  = (const float*)d_in[2];
    const float* W1   = (const float*)d_in[3];
    const float* b1   = (const float*)d_in[4];
    const float* W2   = (const float*)d_in[5];
    const float* b2   = (const float*)d_in[6];

    gnn_fused<<<NBLOCKS, NTHREADS, 0, stream>>>(y, emb, W1, b1, W2, b2,
                                                (float4*)d_out);
}